// Round 4
// baseline (690.903 us; speedup 1.0000x reference)
//
#include <hip/hip_runtime.h>

typedef unsigned short u16;
typedef __attribute__((ext_vector_type(8))) short bf16x8;
typedef __attribute__((ext_vector_type(4))) float f32x4;

#define NHEAD 8
#define SS 2048
#define DMODEL 512
#define MAXG 8192

__device__ __forceinline__ u16 f2bf(float f) {
    unsigned u = __builtin_bit_cast(unsigned, f);
    u = (u + 0x7FFFu + ((u >> 16) & 1u)) >> 16;
    return (u16)u;
}
__device__ __forceinline__ float bf2f(u16 h) {
    unsigned u = ((unsigned)h) << 16;
    return __builtin_bit_cast(float, u);
}

// ---------------- f32 -> bf16 convert (vectorized x4) ----------------
__global__ __launch_bounds__(256) void cvt_kernel(const float* __restrict__ in,
                                                  u16* __restrict__ out, int n4) {
    int i = blockIdx.x * 256 + threadIdx.x;
    if (i >= n4) return;
    float4 v = reinterpret_cast<const float4*>(in)[i];
    ushort4 o;
    o.x = f2bf(v.x); o.y = f2bf(v.y); o.z = f2bf(v.z); o.w = f2bf(v.w);
    reinterpret_cast<ushort4*>(out)[i] = o;
}

// ---------------- gene-pair bias gather: biasb[b][q][k] = gb[gi[b,q]][gi[b,k]] ----------------
__global__ __launch_bounds__(256) void bias_gather(const int* __restrict__ gi,
                                                   const float* __restrict__ gb,
                                                   u16* __restrict__ biasb) {
    __shared__ int gl[SS];
    const int b = blockIdx.y;
    const int q0 = blockIdx.x * 16;
    for (int i = threadIdx.x; i < SS; i += 256) gl[i] = gi[b * SS + i];
    __syncthreads();
    for (int qq = 0; qq < 16; qq++) {
        const int q = q0 + qq;
        const float* row = gb + (size_t)gl[q] * MAXG;
        const size_t obase = ((size_t)b * SS + q) * SS;
        for (int k = threadIdx.x; k < SS; k += 256) {
            biasb[obase + k] = f2bf(row[gl[k]]);
        }
    }
}

// ---------------- QKV projection GEMM: C[m][n] = sum_k X[m][k]*W[n][k] + bias[n] ----------------
// scatter epilogue into qs[b][h][s][d] (x0.125), kb[b][h][s][d], vt[b][h][d][s]
__global__ __launch_bounds__(256) void qkv_gemm(const u16* __restrict__ X,
                                                const u16* __restrict__ W,
                                                const float* __restrict__ bias,
                                                u16* __restrict__ qs,
                                                u16* __restrict__ kb,
                                                u16* __restrict__ vt) {
    __shared__ u16 Xs[128][40];
    __shared__ u16 Ws[128][40];
    const int m0 = blockIdx.x * 128;
    const int n0 = blockIdx.y * 128;
    const int t = threadIdx.x;
    const int lane = t & 63, wid = t >> 6;
    const int wm = wid >> 1, wn = wid & 1;
    const int ql = lane & 15, kg = lane >> 4;
    const int r = t >> 1, half = t & 1;  // staging: 2 threads/row, 16 bf16 each
    f32x4 acc[4][4] = {};
    for (int k0 = 0; k0 < 512; k0 += 32) {
        __syncthreads();
        {
            const uint4* sx = reinterpret_cast<const uint4*>(X + (size_t)(m0 + r) * 512 + k0 + half * 16);
            uint4 a0 = sx[0], a1 = sx[1];
            *reinterpret_cast<uint4*>(&Xs[r][half * 16]) = a0;
            *reinterpret_cast<uint4*>(&Xs[r][half * 16 + 8]) = a1;
            const uint4* sw = reinterpret_cast<const uint4*>(W + (size_t)(n0 + r) * 512 + k0 + half * 16);
            uint4 b0 = sw[0], b1 = sw[1];
            *reinterpret_cast<uint4*>(&Ws[r][half * 16]) = b0;
            *reinterpret_cast<uint4*>(&Ws[r][half * 16 + 8]) = b1;
        }
        __syncthreads();
        bf16x8 a[4], bfr[4];
        for (int mi = 0; mi < 4; mi++)
            a[mi] = *reinterpret_cast<const bf16x8*>(&Xs[wm * 64 + mi * 16 + ql][kg * 8]);
        for (int ni = 0; ni < 4; ni++)
            bfr[ni] = *reinterpret_cast<const bf16x8*>(&Ws[wn * 64 + ni * 16 + ql][kg * 8]);
        for (int mi = 0; mi < 4; mi++)
            for (int ni = 0; ni < 4; ni++)
                acc[mi][ni] = __builtin_amdgcn_mfma_f32_16x16x32_bf16(a[mi], bfr[ni], acc[mi][ni], 0, 0, 0);
    }
    for (int mi = 0; mi < 4; mi++)
        for (int ni = 0; ni < 4; ni++) {
            const int mbase = m0 + wm * 64 + mi * 16 + kg * 4;
            const int n = n0 + wn * 64 + ni * 16 + ql;
            const int region = n >> 9;
            const int h = (n & 511) >> 6, d = n & 63;
            const float bv = bias[n];
            for (int reg = 0; reg < 4; reg++) {
                const int m = mbase + reg;
                const int bidx = m >> 11, s = m & 2047;
                const float v = acc[mi][ni][reg] + bv;
                const size_t bh = (size_t)bidx * NHEAD + h;
                if (region == 0) {
                    qs[(bh * SS + s) * 64 + d] = f2bf(v * 0.125f);
                } else if (region == 1) {
                    kb[(bh * SS + s) * 64 + d] = f2bf(v);
                } else {
                    vt[(bh * 64 + d) * SS + s] = f2bf(v);
                }
            }
        }
}

// ---------------- flash attention w/ additive bias ----------------
// block: 64 q-rows of one (b,h); 4 waves x 16 rows. K-tiles of 32.
__global__ __launch_bounds__(256) void attn_kernel(const u16* __restrict__ qs,
                                                   const u16* __restrict__ kb,
                                                   const u16* __restrict__ vt,
                                                   const u16* __restrict__ biasb,
                                                   u16* __restrict__ aout) {
    __shared__ u16 plds[4][16][40];
    const int t = threadIdx.x, lane = t & 63, w = t >> 6;
    const int q0 = blockIdx.x * 64;
    const int h = blockIdx.y;
    const int b = blockIdx.z;
    const size_t bh = (size_t)b * NHEAD + h;
    const u16* Q = qs + bh * SS * 64;
    const u16* K = kb + bh * SS * 64;
    const u16* V = vt + bh * 64 * SS;
    const u16* BIA = biasb + (size_t)b * SS * SS;
    const int ql = lane & 15;  // A-frag row / C-frag col
    const int kg = lane >> 4;  // lane group
    bf16x8 qf[2];
    {
        const u16* qrow = Q + (size_t)(q0 + w * 16 + ql) * 64 + kg * 8;
        qf[0] = *reinterpret_cast<const bf16x8*>(qrow);
        qf[1] = *reinterpret_cast<const bf16x8*>(qrow + 32);
    }
    f32x4 o[4] = {};
    float m[4], l[4];
    for (int i = 0; i < 4; i++) { m[i] = -1e30f; l[i] = 0.f; }
    const int qrow_base = q0 + w * 16 + kg * 4;  // + reg -> global q row of C-frag
    const float LOG2E = 1.4426950408889634f;

    for (int kt = 0; kt < SS; kt += 32) {
        // S = Q K^T (scale pre-folded into Q)
        f32x4 s[2] = {};
        for (int j = 0; j < 2; j++) {
            const u16* krow = K + (size_t)(kt + j * 16 + ql) * 64 + kg * 8;
            bf16x8 kf0 = *reinterpret_cast<const bf16x8*>(krow);
            bf16x8 kf1 = *reinterpret_cast<const bf16x8*>(krow + 32);
            s[j] = __builtin_amdgcn_mfma_f32_16x16x32_bf16(qf[0], kf0, s[j], 0, 0, 0);
            s[j] = __builtin_amdgcn_mfma_f32_16x16x32_bf16(qf[1], kf1, s[j], 0, 0, 0);
        }
        // add gathered gene-pair bias
        for (int j = 0; j < 2; j++)
            for (int reg = 0; reg < 4; reg++) {
                const int qg = qrow_base + reg;
                const int kgl = kt + j * 16 + ql;
                s[j][reg] += bf2f(BIA[(size_t)qg * SS + kgl]);
            }
        // online softmax (rows live on 16-lane groups)
        float p[2][4];
        for (int reg = 0; reg < 4; reg++) {
            float v = fmaxf(s[0][reg], s[1][reg]);
            v = fmaxf(v, __shfl_xor(v, 1));
            v = fmaxf(v, __shfl_xor(v, 2));
            v = fmaxf(v, __shfl_xor(v, 4));
            v = fmaxf(v, __shfl_xor(v, 8));
            const float mn = fmaxf(m[reg], v);
            const float alpha = exp2f((m[reg] - mn) * LOG2E);
            float ps = 0.f;
            for (int j = 0; j < 2; j++) {
                const float pv = exp2f((s[j][reg] - mn) * LOG2E);
                p[j][reg] = pv;
                ps += pv;
            }
            ps += __shfl_xor(ps, 1);
            ps += __shfl_xor(ps, 2);
            ps += __shfl_xor(ps, 4);
            ps += __shfl_xor(ps, 8);
            l[reg] = l[reg] * alpha + ps;
            m[reg] = mn;
            for (int dc = 0; dc < 4; dc++) o[dc][reg] *= alpha;
        }
        // transpose P through per-wave LDS (C-layout -> A-layout)
        for (int j = 0; j < 2; j++)
            for (int reg = 0; reg < 4; reg++)
                plds[w][kg * 4 + reg][j * 16 + ql] = f2bf(p[j][reg]);
        bf16x8 pf = *reinterpret_cast<const bf16x8*>(&plds[w][ql][kg * 8]);
        // O += P V  (V stored transposed: vt[d][s])
        for (int dc = 0; dc < 4; dc++) {
            const u16* vrow = V + (size_t)(dc * 16 + ql) * SS + kt + kg * 8;
            bf16x8 vf = *reinterpret_cast<const bf16x8*>(vrow);
            o[dc] = __builtin_amdgcn_mfma_f32_16x16x32_bf16(pf, vf, o[dc], 0, 0, 0);
        }
    }
    // epilogue: normalize, write aout[b][s][h*64+d]
    for (int reg = 0; reg < 4; reg++) {
        const float inv = 1.0f / l[reg];
        const int sg = qrow_base + reg;
        const size_t base = ((size_t)b * SS + sg) * DMODEL + h * 64;
        for (int dc = 0; dc < 4; dc++)
            aout[base + dc * 16 + ql] = f2bf(o[dc][reg] * inv);
    }
}

// ---------------- out projection GEMM: out[m][n] = sum_k A[m][k]*W[n][k] + bias[n] ----------------
__global__ __launch_bounds__(256) void out_gemm(const u16* __restrict__ X,
                                                const u16* __restrict__ W,
                                                const float* __restrict__ bias,
                                                float* __restrict__ out) {
    __shared__ u16 Xs[128][40];
    __shared__ u16 Ws[128][40];
    const int m0 = blockIdx.x * 128;
    const int n0 = blockIdx.y * 128;
    const int t = threadIdx.x;
    const int lane = t & 63, wid = t >> 6;
    const int wm = wid >> 1, wn = wid & 1;
    const int ql = lane & 15, kg = lane >> 4;
    const int r = t >> 1, half = t & 1;
    f32x4 acc[4][4] = {};
    for (int k0 = 0; k0 < 512; k0 += 32) {
        __syncthreads();
        {
            const uint4* sx = reinterpret_cast<const uint4*>(X + (size_t)(m0 + r) * 512 + k0 + half * 16);
            uint4 a0 = sx[0], a1 = sx[1];
            *reinterpret_cast<uint4*>(&Xs[r][half * 16]) = a0;
            *reinterpret_cast<uint4*>(&Xs[r][half * 16 + 8]) = a1;
            const uint4* sw = reinterpret_cast<const uint4*>(W + (size_t)(n0 + r) * 512 + k0 + half * 16);
            uint4 b0 = sw[0], b1 = sw[1];
            *reinterpret_cast<uint4*>(&Ws[r][half * 16]) = b0;
            *reinterpret_cast<uint4*>(&Ws[r][half * 16 + 8]) = b1;
        }
        __syncthreads();
        bf16x8 a[4], bfr[4];
        for (int mi = 0; mi < 4; mi++)
            a[mi] = *reinterpret_cast<const bf16x8*>(&Xs[wm * 64 + mi * 16 + ql][kg * 8]);
        for (int ni = 0; ni < 4; ni++)
            bfr[ni] = *reinterpret_cast<const bf16x8*>(&Ws[wn * 64 + ni * 16 + ql][kg * 8]);
        for (int mi = 0; mi < 4; mi++)
            for (int ni = 0; ni < 4; ni++)
                acc[mi][ni] = __builtin_amdgcn_mfma_f32_16x16x32_bf16(a[mi], bfr[ni], acc[mi][ni], 0, 0, 0);
    }
    for (int mi = 0; mi < 4; mi++)
        for (int ni = 0; ni < 4; ni++) {
            const int mbase = m0 + wm * 64 + mi * 16 + kg * 4;
            const int n = n0 + wn * 64 + ni * 16 + ql;
            const float bv = bias[n];
            for (int reg = 0; reg < 4; reg++) {
                const int m = mbase + reg;
                out[(size_t)m * DMODEL + n] = acc[mi][ni][reg] + bv;
            }
        }
}

extern "C" void kernel_launch(void* const* d_in, const int* in_sizes, int n_in,
                              void* d_out, int out_size, void* d_ws, size_t ws_size,
                              hipStream_t stream) {
    const float* query = (const float*)d_in[0];
    const int* gidx = (const int*)d_in[1];
    const float* ipw = (const float*)d_in[2];
    const float* ipb = (const float*)d_in[3];
    const float* outw = (const float*)d_in[4];
    const float* outb = (const float*)d_in[5];
    const float* gbias = (const float*)d_in[6];

    char* ws = (char*)d_ws;
    u16* qbf  = (u16*)(ws + 0);         // query bf16      8 MB
    u16* wbf  = (u16*)(ws + 8388608);   // in_proj bf16    1.5 MB
    u16* w2bf = (u16*)(ws + 9961472);   // out_w bf16      0.5 MB
    u16* qsb  = (u16*)(ws + 10485760);  // Q scaled        8 MB
    u16* kbb  = (u16*)(ws + 18874368);  // K               8 MB
    u16* vtb  = (u16*)(ws + 27262976);  // V transposed    8 MB
    u16* aout = (u16*)(ws + 35651584);  // attn out        8 MB
    u16* bb   = (u16*)(ws + 44040192);  // gathered bias   32 MB

    cvt_kernel<<<dim3(4096), dim3(256), 0, stream>>>(query, qbf, 1048576);
    cvt_kernel<<<dim3(768), dim3(256), 0, stream>>>(ipw, wbf, 196608);
    cvt_kernel<<<dim3(256), dim3(256), 0, stream>>>(outw, w2bf, 65536);
    bias_gather<<<dim3(128, 4), dim3(256), 0, stream>>>(gidx, gbias, bb);
    qkv_gemm<<<dim3(64, 12), dim3(256), 0, stream>>>(qbf, wbf, ipb, qsb, kbb, vtb);
    attn_kernel<<<dim3(32, 8, 4), dim3(256), 0, stream>>>(qsb, kbb, vtb, bb, aout);
    out_gemm<<<dim3(64, 4), dim3(256), 0, stream>>>(aout, w2bf, outb, (float*)d_out);
}